// Round 10
// baseline (1714.622 us; speedup 1.0000x reference)
//
#include <hip/hip_runtime.h>
#include <hip/hip_bf16.h>

typedef _Float16 f16;
typedef _Float16 f16x2 __attribute__((ext_vector_type(2)));
typedef _Float16 f16x4 __attribute__((ext_vector_type(4)));
typedef _Float16 f16x8 __attribute__((ext_vector_type(8)));

#define BATCH 128
#define SEQ   1024
#define IND   256
#define HID   512

#if defined(__has_builtin)
#if __has_builtin(__builtin_amdgcn_fdot2)
#define HAVE_FDOT2 1
#endif
#endif

__device__ __forceinline__ float fdot2(f16x2 a, f16x2 b, float c) {
#ifdef HAVE_FDOT2
  return __builtin_amdgcn_fdot2(a, b, c, false);
#else
  return c + (float)a[0] * (float)b[0] + (float)a[1] * (float)b[1];
#endif
}

union v8u {
  f16x8 v;
  f16x2 h[4];
};

__device__ __forceinline__ float tanh_fast(float s) {
  float e = __expf(2.0f * s);
  return 1.0f - 2.0f / (e + 1.0f);
}

// cross-lane float move via DPP; all lanes active required
template <int CTRL>
__device__ __forceinline__ float fdpp(float x) {
  int i = __builtin_bit_cast(int, x);
  i = __builtin_amdgcn_mov_dpp(i, CTRL, 0xf, 0xf, false);
  return __builtin_bit_cast(float, i);
}

// ---------------------------------------------------------------------------
// prep: W_su f32 [768][512] -> WzT f16 [h=512][k=512], WxT f16 [h=512][d=256]
// ---------------------------------------------------------------------------
__global__ __launch_bounds__(256) void prep_kernel(const float* __restrict__ Wsu,
                                                   f16* __restrict__ WzT,
                                                   f16* __restrict__ WxT) {
  int g = blockIdx.x * 256 + threadIdx.x;  // 0 .. 768*512-1
  int k = g >> 9;
  int h = g & 511;
  float v = Wsu[g];
  if (k < HID) WzT[h * HID + k] = (f16)v;
  else         WxT[h * IND + (k - HID)] = (f16)v;
}

// ---------------------------------------------------------------------------
// gemm1: xw[m][n] = sum_k x[m][k] * WxT[n][k] + bsu[n]   (f16 dot2, 64x64 tile)
// ---------------------------------------------------------------------------
__global__ __launch_bounds__(256) void gemm1_kernel(const float* __restrict__ x,
                                                    const f16* __restrict__ WxT,
                                                    const float* __restrict__ bsu,
                                                    f16* __restrict__ xw) {
  __shared__ __align__(16) f16x2 X2[16][64];  // [k-pair][row]
  __shared__ __align__(16) f16x2 W2[16][64];  // [k-pair][col]
  int m0 = blockIdx.x * 64, n0 = blockIdx.y * 64;
  int tid = threadIdx.x;
  int cg = tid & 15;
  int rg = tid >> 4;
  int sr = tid >> 2;
  int q  = tid & 3;

  float4 bv = *(const float4*)&bsu[n0 + cg * 4];
  float bj[4] = {bv.x, bv.y, bv.z, bv.w};
  float acc[4][4];
#pragma unroll
  for (int i = 0; i < 4; ++i)
#pragma unroll
    for (int j = 0; j < 4; ++j) acc[i][j] = bj[j];

  for (int ks = 0; ks < 8; ++ks) {
    int k0 = ks * 32;
    const float4* xp = (const float4*)&x[(m0 + sr) * IND + k0 + q * 8];
    float4 a0 = xp[0], a1 = xp[1];
    X2[q * 4 + 0][sr] = (f16x2){(f16)a0.x, (f16)a0.y};
    X2[q * 4 + 1][sr] = (f16x2){(f16)a0.z, (f16)a0.w};
    X2[q * 4 + 2][sr] = (f16x2){(f16)a1.x, (f16)a1.y};
    X2[q * 4 + 3][sr] = (f16x2){(f16)a1.z, (f16)a1.w};
    v8u wv;
    wv.v = *(const f16x8*)&WxT[(n0 + sr) * IND + k0 + q * 8];
#pragma unroll
    for (int p = 0; p < 4; ++p) W2[q * 4 + p][sr] = wv.h[p];
    __syncthreads();
#pragma unroll
    for (int kk = 0; kk < 16; ++kk) {
      v8u xv, wvv;
      xv.v = *(const f16x8*)&X2[kk][rg * 4];
      wvv.v = *(const f16x8*)&W2[kk][cg * 4];
#pragma unroll
      for (int i = 0; i < 4; ++i) {
        f16x2 xi = xv.h[i];
#pragma unroll
        for (int j = 0; j < 4; ++j) {
          acc[i][j] = fdot2(xi, wvv.h[j], acc[i][j]);
        }
      }
    }
    __syncthreads();
  }
#pragma unroll
  for (int i = 0; i < 4; ++i) {
    int row = m0 + rg * 4 + i;
    f16x4 o = {(f16)acc[i][0], (f16)acc[i][1], (f16)acc[i][2], (f16)acc[i][3]};
    *(f16x4*)&xw[row * HID + n0 + cg * 4] = o;
  }
}

// ---------------------------------------------------------------------------
// scan v6: 128 blocks (1 batch) x 512 threads (8 waves, 2/SIMD, 256-reg cap).
// Lane map: w=tid>>6, l=tid&63; kc=l&7 (64-k chunk); hq=l>>3 (row octet);
// thread owns rows hbase=w*64+hq*8 .. +7, k in [kc*64, kc*64+64).
// Rows 0..6 register-resident (224 VGPR); row 7 streamed from LDS
// wl[s][tid] (64 KB/step, conflict-free contiguous b128).
// z-reads: 8 swizzled broadcast b128 (slice (s^kc) -> 32 banks covered).
// Cross-chunk reduce fully in-register (R8/R9-validated pack-reduce):
//   xor7 (dpp 0x141) -> xor1 (0xB1) -> xor2 (0x4E).
// Lane l ends with row hbase + 4*b2+2*b0+b1; ALL 512 lanes tanh+write.
// zsh double-buffered => ONE barrier per step. LDS total ~68 KB.
// ---------------------------------------------------------------------------
__global__ __launch_bounds__(512, 2) void scan_kernel(
    const f16* __restrict__ WzT, const f16* __restrict__ xw,
    const float* __restrict__ carry, const float* __restrict__ Wout,
    const float* __restrict__ bout, float* __restrict__ outp) {
  __shared__ __align__(16) f16 zsh[2][512];        // 2 KB double-buffered z
  __shared__ __align__(16) f16x8 wl[8][512];       // 64 KB row-7 weights
  __shared__ float red[512];                       // 2 KB epilogue

  const int b_ = blockIdx.x;
  const int tid = threadIdx.x;
  const int w = tid >> 6, l = tid & 63;
  const int kc = l & 7;
  const int hq = l >> 3;
  const int hbase = w * 64 + hq * 8;

  // rows hbase..hbase+6 -> registers (224 VGPRs), slice-permuted by (s^kc)
  f16x2 wreg[7][32];
#pragma unroll
  for (int r = 0; r < 7; ++r) {
#pragma unroll
    for (int s = 0; s < 8; ++s) {
      v8u v;
      v.v = *(const f16x8*)&WzT[(hbase + r) * HID + kc * 64 + ((s ^ kc) & 7) * 8];
#pragma unroll
      for (int p = 0; p < 4; ++p) wreg[r][s * 4 + p] = v.h[p];
    }
  }
  // opacity pin: prevent remat/sinking
#pragma unroll
  for (int r = 0; r < 7; ++r) {
#pragma unroll
    for (int s = 0; s < 32; ++s) {
      unsigned u = __builtin_bit_cast(unsigned, wreg[r][s]);
      asm volatile("" : "+v"(u));
      wreg[r][s] = __builtin_bit_cast(f16x2, u);
    }
  }
  // row hbase+7 -> LDS in consumption order
#pragma unroll
  for (int s = 0; s < 8; ++s)
    wl[s][tid] = *(const f16x8*)&WzT[(hbase + 7) * HID + kc * 64 + ((s ^ kc) & 7) * 8];

  // z^0 from carry, plain layout
  zsh[0][tid] = (f16)carry[b_ * HID + tid];

  // output row after pack-reduce: hbase + 4*b2 + 2*b0 + b1
  const int b0 = l & 1, b1 = (l >> 1) & 1, b2 = (l >> 2) & 1;
  const int myh = hbase + (b2 << 2) + (b0 << 1) + b1;

  float xw_cur = (float)xw[(size_t)b_ * SEQ * HID + myh];

  __syncthreads();

  float zlast = 0.f;
  for (int t = 0; t < SEQ; ++t) {
    const int p = t & 1;
    int tn = (t + 1 < SEQ) ? t + 1 : t;
    float xw_nxt = (float)xw[((size_t)b_ * SEQ + tn) * HID + myh];

    const f16* zb = &zsh[p][kc * 64];
    float a0 = 0.f, a1 = 0.f, a2 = 0.f, a3 = 0.f;
    float a4 = 0.f, a5 = 0.f, a6 = 0.f, a7 = 0.f;
#pragma unroll
    for (int s = 0; s < 8; ++s) {
      v8u zc, w7;
      zc.v = *(const f16x8*)&zb[((s ^ kc) & 7) * 8];  // broadcast, bank-spread
      w7.v = wl[s][tid];
#pragma unroll
      for (int q4 = 0; q4 < 4; ++q4) {
        f16x2 zp = zc.h[q4];
        int pi = s * 4 + q4;
        a0 = fdot2(zp, wreg[0][pi], a0);
        a1 = fdot2(zp, wreg[1][pi], a1);
        a2 = fdot2(zp, wreg[2][pi], a2);
        a3 = fdot2(zp, wreg[3][pi], a3);
        a4 = fdot2(zp, wreg[4][pi], a4);
        a5 = fdot2(zp, wreg[5][pi], a5);
        a6 = fdot2(zp, wreg[6][pi], a6);
        a7 = fdot2(zp, w7.h[q4], a7);
      }
    }

    // ---- in-register pack-reduce over kc (lane bits 0,1,2) ----
    // stage xor7 (dpp 0x141 = row_half_mirror), keep-select by b2
    float n0_ = b2 ? a4 : a0, s0_ = b2 ? a0 : a4;
    float n1_ = b2 ? a5 : a1, s1_ = b2 ? a1 : a5;
    float n2_ = b2 ? a6 : a2, s2_ = b2 ? a2 : a6;
    float n3_ = b2 ? a7 : a3, s3_ = b2 ? a3 : a7;
    n0_ += fdpp<0x141>(s0_);
    n1_ += fdpp<0x141>(s1_);
    n2_ += fdpp<0x141>(s2_);
    n3_ += fdpp<0x141>(s3_);
    // stage xor1 (quad_perm [1,0,3,2] = 0xB1), keep-select by b0
    float m0_ = b0 ? n2_ : n0_, t0_ = b0 ? n0_ : n2_;
    float m1_ = b0 ? n3_ : n1_, t1_ = b0 ? n1_ : n3_;
    m0_ += fdpp<0xB1>(t0_);
    m1_ += fdpp<0xB1>(t1_);
    // stage xor2 (quad_perm [2,3,0,1] = 0x4E), keep-select by b1
    float f0_ = b1 ? m1_ : m0_, g0_ = b1 ? m0_ : m1_;
    float tot = f0_ + fdpp<0x4E>(g0_);
    // lane holds full sum for row myh

    float z = tanh_fast(tot + xw_cur);
    zlast = z;
    zsh[p ^ 1][myh] = (f16)z;
    __syncthreads();
    xw_cur = xw_nxt;
  }

  // outputs: z_last (f32, exact from register) + out[b] GEMV
  outp[BATCH + (size_t)b_ * HID + myh] = zlast;
  red[myh] = zlast * Wout[myh];
  __syncthreads();
  if (tid < 64) {
    float s2 = 0.f;
#pragma unroll
    for (int i = 0; i < 8; ++i) s2 += red[tid + 64 * i];
    red[tid] = s2;
  }
  __syncthreads();
  if (tid == 0) {
    float s3 = 0.f;
    for (int i = 0; i < 64; ++i) s3 += red[i];
    outp[b_] = s3 + bout[0];
  }
}

// ---------------------------------------------------------------------------
extern "C" void kernel_launch(void* const* d_in, const int* in_sizes, int n_in,
                              void* d_out, int out_size, void* d_ws, size_t ws_size,
                              hipStream_t stream) {
  const float* x     = (const float*)d_in[0];
  const float* carry = (const float*)d_in[1];
  const float* Wsu   = (const float*)d_in[2];
  const float* bsu   = (const float*)d_in[3];
  const float* Wout  = (const float*)d_in[4];
  const float* bout  = (const float*)d_in[5];
  float* outp = (float*)d_out;

  char* ws = (char*)d_ws;
  f16* WzT = (f16*)(ws);                        // 512 KB
  f16* WxT = (f16*)(ws + 512 * 1024);           // 256 KB
  f16* xw  = (f16*)(ws + 768 * 1024);           // 128 MB (131072*512*2B)

  prep_kernel<<<dim3((768 * 512) / 256), 256, 0, stream>>>(Wsu, WzT, WxT);
  gemm1_kernel<<<dim3(BATCH * SEQ / 64, HID / 64), 256, 0, stream>>>(x, WxT, bsu, xw);
  scan_kernel<<<dim3(BATCH), 512, 0, stream>>>(WzT, xw, carry, Wout, bout, outp);
}

// Round 11
// 1692.153 us; speedup vs baseline: 1.0133x; 1.0133x over previous
//
#include <hip/hip_runtime.h>
#include <hip/hip_bf16.h>

typedef _Float16 f16;
typedef _Float16 f16x2 __attribute__((ext_vector_type(2)));
typedef _Float16 f16x4 __attribute__((ext_vector_type(4)));
typedef _Float16 f16x8 __attribute__((ext_vector_type(8)));
typedef float f32x4 __attribute__((ext_vector_type(4)));

#define BATCH 128
#define SEQ   1024
#define IND   256
#define HID   512

#if defined(__has_builtin)
#if __has_builtin(__builtin_amdgcn_fdot2)
#define HAVE_FDOT2 1
#endif
#endif

__device__ __forceinline__ float fdot2(f16x2 a, f16x2 b, float c) {
#ifdef HAVE_FDOT2
  return __builtin_amdgcn_fdot2(a, b, c, false);
#else
  return c + (float)a[0] * (float)b[0] + (float)a[1] * (float)b[1];
#endif
}

union v8u {
  f16x8 v;
  f16x2 h[4];
};

__device__ __forceinline__ float tanh_fast(float s) {
  float e = __expf(2.0f * s);
  return 1.0f - 2.0f / (e + 1.0f);
}

// cross-lane float move via DPP; all lanes active required
template <int CTRL>
__device__ __forceinline__ float fdpp(float x) {
  int i = __builtin_bit_cast(int, x);
  i = __builtin_amdgcn_mov_dpp(i, CTRL, 0xf, 0xf, false);
  return __builtin_bit_cast(float, i);
}

// ---------------------------------------------------------------------------
// prep: W_su f32 [768][512] -> WzT f16 [h=512][k=512], WxT f16 [h=512][d=256]
// ---------------------------------------------------------------------------
__global__ __launch_bounds__(256) void prep_kernel(const float* __restrict__ Wsu,
                                                   f16* __restrict__ WzT,
                                                   f16* __restrict__ WxT) {
  int g = blockIdx.x * 256 + threadIdx.x;  // 0 .. 768*512-1
  int k = g >> 9;
  int h = g & 511;
  float v = Wsu[g];
  if (k < HID) WzT[h * HID + k] = (f16)v;
  else         WxT[h * IND + (k - HID)] = (f16)v;
}

// ---------------------------------------------------------------------------
// gemm1 (MFMA): xw[m][n] = sum_k x[m][k]*WxT[n][k] + bsu[n]
// mfma_f32_16x16x32_f16; 64x64 tile per 256-thread block (4 waves).
// wave w owns rows m0+16w..+15; 4 n-tiles of 16; K=256 in 8 steps of 32.
// A frag: lane row=l&15, k=kg*8..+7 (kg=l>>4) from x (f32 -> cvt f16).
// B frag: lane col=l&15, same k-slice, f16x8 straight from WxT (k-contig).
// C/D layout (m89-verified): col=lane&15, row=(lane>>4)*4+reg.
// ---------------------------------------------------------------------------
__global__ __launch_bounds__(256) void gemm1_kernel(const float* __restrict__ x,
                                                    const f16* __restrict__ WxT,
                                                    const float* __restrict__ bsu,
                                                    f16* __restrict__ xw) {
  const int m0 = blockIdx.x * 64, n0 = blockIdx.y * 64;
  const int w = threadIdx.x >> 6, l = threadIdx.x & 63;
  const int r16 = l & 15;   // A-row / B-col within tile
  const int kg  = l >> 4;   // k-subgroup (8 wide)

  const int arow = m0 + w * 16 + r16;

  f32x4 acc[4];
#pragma unroll
  for (int nt = 0; nt < 4; ++nt) {
    float bv = bsu[n0 + nt * 16 + r16];
    acc[nt] = (f32x4){bv, bv, bv, bv};
  }

#pragma unroll
  for (int kb = 0; kb < 8; ++kb) {
    const int k0 = kb * 32 + kg * 8;
    // A fragment: 8 consecutive f32 -> f16x8
    const float4* ap = (const float4*)&x[(size_t)arow * IND + k0];
    float4 a0 = ap[0], a1 = ap[1];
    f16x8 afrag = {(f16)a0.x, (f16)a0.y, (f16)a0.z, (f16)a0.w,
                   (f16)a1.x, (f16)a1.y, (f16)a1.z, (f16)a1.w};
#pragma unroll
    for (int nt = 0; nt < 4; ++nt) {
      f16x8 bfrag = *(const f16x8*)&WxT[(size_t)(n0 + nt * 16 + r16) * IND + k0];
      acc[nt] = __builtin_amdgcn_mfma_f32_16x16x32_f16(afrag, bfrag, acc[nt], 0, 0, 0);
    }
  }

  // store: row = m0+16w + (l>>4)*4 + r, col = n0+nt*16+(l&15)
#pragma unroll
  for (int nt = 0; nt < 4; ++nt) {
#pragma unroll
    for (int r = 0; r < 4; ++r) {
      int grow = m0 + w * 16 + kg * 4 + r;
      int gcol = n0 + nt * 16 + r16;
      xw[(size_t)grow * HID + gcol] = (f16)acc[nt][r];
    }
  }
}

// ---------------------------------------------------------------------------
// scan v5 (R9, proven 1410us): 128 blocks x 512 threads (8 waves, 2/SIMD).
// Lane map: w=tid>>6, l=tid&63; kc=l&7 (64-k chunk); hq=l>>3 (row octet);
// thread owns rows hbase=w*64+hq*8 .. +7, k in [kc*64, kc*64+64).
// Rows 0..5 register-resident (192 f16x2); rows 6,7 streamed from LDS
// wl6/wl7[s][tid] (conflict-free contiguous b128).
// z-reads: 8 swizzled broadcast b128. Cross-chunk reduce in-register:
// xor7 (dpp 0x141) -> xor1 (0xB1) -> xor2 (0x4E). ONE barrier per step.
// ---------------------------------------------------------------------------
__global__ __launch_bounds__(512, 2) void scan_kernel(
    const f16* __restrict__ WzT, const f16* __restrict__ xw,
    const float* __restrict__ carry, const float* __restrict__ Wout,
    const float* __restrict__ bout, float* __restrict__ outp) {
  __shared__ __align__(16) f16 zsh[2][512];        // 2 KB double-buffered z
  __shared__ __align__(16) f16x8 wl6[8][512];      // 64 KB row-6 weights
  __shared__ __align__(16) f16x8 wl7[8][512];      // 64 KB row-7 weights
  __shared__ float red[512];                       // 2 KB epilogue

  const int b_ = blockIdx.x;
  const int tid = threadIdx.x;
  const int w = tid >> 6, l = tid & 63;
  const int kc = l & 7;
  const int hq = l >> 3;
  const int hbase = w * 64 + hq * 8;

  // rows hbase..hbase+5 -> registers, slice-permuted by (s^kc)
  f16x2 wreg[6][32];
#pragma unroll
  for (int r = 0; r < 6; ++r) {
#pragma unroll
    for (int s = 0; s < 8; ++s) {
      v8u v;
      v.v = *(const f16x8*)&WzT[(hbase + r) * HID + kc * 64 + ((s ^ kc) & 7) * 8];
#pragma unroll
      for (int p = 0; p < 4; ++p) wreg[r][s * 4 + p] = v.h[p];
    }
  }
  // opacity pin: prevent remat/sinking
#pragma unroll
  for (int r = 0; r < 6; ++r) {
#pragma unroll
    for (int s = 0; s < 32; ++s) {
      unsigned u = __builtin_bit_cast(unsigned, wreg[r][s]);
      asm volatile("" : "+v"(u));
      wreg[r][s] = __builtin_bit_cast(f16x2, u);
    }
  }
  // rows hbase+6, hbase+7 -> LDS in consumption order
#pragma unroll
  for (int s = 0; s < 8; ++s) {
    wl6[s][tid] = *(const f16x8*)&WzT[(hbase + 6) * HID + kc * 64 + ((s ^ kc) & 7) * 8];
    wl7[s][tid] = *(const f16x8*)&WzT[(hbase + 7) * HID + kc * 64 + ((s ^ kc) & 7) * 8];
  }

  // z^0 from carry, plain layout
  zsh[0][tid] = (f16)carry[b_ * HID + tid];

  // output row after pack-reduce: hbase + 4*b2 + 2*b0 + b1
  const int b0 = l & 1, b1 = (l >> 1) & 1, b2 = (l >> 2) & 1;
  const int myh = hbase + (b2 << 2) + (b0 << 1) + b1;

  float xw_cur = (float)xw[(size_t)b_ * SEQ * HID + myh];

  __syncthreads();

  float zlast = 0.f;
  for (int t = 0; t < SEQ; ++t) {
    const int p = t & 1;
    int tn = (t + 1 < SEQ) ? t + 1 : t;
    float xw_nxt = (float)xw[((size_t)b_ * SEQ + tn) * HID + myh];

    const f16* zb = &zsh[p][kc * 64];
    float a0 = 0.f, a1 = 0.f, a2 = 0.f, a3 = 0.f;
    float a4 = 0.f, a5 = 0.f, a6 = 0.f, a7 = 0.f;
#pragma unroll
    for (int s = 0; s < 8; ++s) {
      v8u zc, w6, w7;
      zc.v = *(const f16x8*)&zb[((s ^ kc) & 7) * 8];  // broadcast, bank-spread
      w6.v = wl6[s][tid];
      w7.v = wl7[s][tid];
#pragma unroll
      for (int q4 = 0; q4 < 4; ++q4) {
        f16x2 zp = zc.h[q4];
        int pi = s * 4 + q4;
        a0 = fdot2(zp, wreg[0][pi], a0);
        a1 = fdot2(zp, wreg[1][pi], a1);
        a2 = fdot2(zp, wreg[2][pi], a2);
        a3 = fdot2(zp, wreg[3][pi], a3);
        a4 = fdot2(zp, wreg[4][pi], a4);
        a5 = fdot2(zp, wreg[5][pi], a5);
        a6 = fdot2(zp, w6.h[q4], a6);
        a7 = fdot2(zp, w7.h[q4], a7);
      }
    }

    // ---- in-register pack-reduce over kc (lane bits 0,1,2) ----
    float n0_ = b2 ? a4 : a0, s0_ = b2 ? a0 : a4;
    float n1_ = b2 ? a5 : a1, s1_ = b2 ? a1 : a5;
    float n2_ = b2 ? a6 : a2, s2_ = b2 ? a2 : a6;
    float n3_ = b2 ? a7 : a3, s3_ = b2 ? a3 : a7;
    n0_ += fdpp<0x141>(s0_);
    n1_ += fdpp<0x141>(s1_);
    n2_ += fdpp<0x141>(s2_);
    n3_ += fdpp<0x141>(s3_);
    float m0_ = b0 ? n2_ : n0_, t0_ = b0 ? n0_ : n2_;
    float m1_ = b0 ? n3_ : n1_, t1_ = b0 ? n1_ : n3_;
    m0_ += fdpp<0xB1>(t0_);
    m1_ += fdpp<0xB1>(t1_);
    float f0_ = b1 ? m1_ : m0_, g0_ = b1 ? m0_ : m1_;
    float tot = f0_ + fdpp<0x4E>(g0_);

    float z = tanh_fast(tot + xw_cur);
    zlast = z;
    zsh[p ^ 1][myh] = (f16)z;
    __syncthreads();
    xw_cur = xw_nxt;
  }

  // outputs: z_last (f32, exact from register) + out[b] GEMV
  outp[BATCH + (size_t)b_ * HID + myh] = zlast;
  red[myh] = zlast * Wout[myh];
  __syncthreads();
  if (tid < 64) {
    float s2 = 0.f;
#pragma unroll
    for (int i = 0; i < 8; ++i) s2 += red[tid + 64 * i];
    red[tid] = s2;
  }
  __syncthreads();
  if (tid == 0) {
    float s3 = 0.f;
    for (int i = 0; i < 64; ++i) s3 += red[i];
    outp[b_] = s3 + bout[0];
  }
}

// ---------------------------------------------------------------------------
extern "C" void kernel_launch(void* const* d_in, const int* in_sizes, int n_in,
                              void* d_out, int out_size, void* d_ws, size_t ws_size,
                              hipStream_t stream) {
  const float* x     = (const float*)d_in[0];
  const float* carry = (const float*)d_in[1];
  const float* Wsu   = (const float*)d_in[2];
  const float* bsu   = (const float*)d_in[3];
  const float* Wout  = (const float*)d_in[4];
  const float* bout  = (const float*)d_in[5];
  float* outp = (float*)d_out;

  char* ws = (char*)d_ws;
  f16* WzT = (f16*)(ws);                        // 512 KB
  f16* WxT = (f16*)(ws + 512 * 1024);           // 256 KB
  f16* xw  = (f16*)(ws + 768 * 1024);           // 128 MB (131072*512*2B)

  prep_kernel<<<dim3((768 * 512) / 256), 256, 0, stream>>>(Wsu, WzT, WxT);
  gemm1_kernel<<<dim3(BATCH * SEQ / 64, HID / 64), 256, 0, stream>>>(x, WxT, bsu, xw);
  scan_kernel<<<dim3(BATCH), 512, 0, stream>>>(WzT, xw, carry, Wout, bout, outp);
}

// Round 12
// 1439.951 us; speedup vs baseline: 1.1907x; 1.1751x over previous
//
#include <hip/hip_runtime.h>
#include <hip/hip_bf16.h>

typedef _Float16 f16;
typedef _Float16 f16x2 __attribute__((ext_vector_type(2)));
typedef _Float16 f16x4 __attribute__((ext_vector_type(4)));
typedef _Float16 f16x8 __attribute__((ext_vector_type(8)));
typedef float f32x4 __attribute__((ext_vector_type(4)));

#define BATCH 128
#define SEQ   1024
#define IND   256
#define HID   512

#if defined(__has_builtin)
#if __has_builtin(__builtin_amdgcn_fdot2)
#define HAVE_FDOT2 1
#endif
#endif

__device__ __forceinline__ float fdot2(f16x2 a, f16x2 b, float c) {
#ifdef HAVE_FDOT2
  return __builtin_amdgcn_fdot2(a, b, c, false);
#else
  return c + (float)a[0] * (float)b[0] + (float)a[1] * (float)b[1];
#endif
}

union v8u {
  f16x8 v;
  f16x2 h[4];
};

__device__ __forceinline__ float tanh_fast(float s) {
  float e = __expf(2.0f * s);
  return 1.0f - 2.0f / (e + 1.0f);
}

// cross-lane float move via DPP; all lanes active required
template <int CTRL>
__device__ __forceinline__ float fdpp(float x) {
  int i = __builtin_bit_cast(int, x);
  i = __builtin_amdgcn_mov_dpp(i, CTRL, 0xf, 0xf, false);
  return __builtin_bit_cast(float, i);
}

// ---------------------------------------------------------------------------
// prep: W_su f32 [768][512] -> WzT f16 [h=512][k=512], WxT f16 [h=512][d=256]
// ---------------------------------------------------------------------------
__global__ __launch_bounds__(256) void prep_kernel(const float* __restrict__ Wsu,
                                                   f16* __restrict__ WzT,
                                                   f16* __restrict__ WxT) {
  int g = blockIdx.x * 256 + threadIdx.x;  // 0 .. 768*512-1
  int k = g >> 9;
  int h = g & 511;
  float v = Wsu[g];
  if (k < HID) WzT[h * HID + k] = (f16)v;
  else         WxT[h * IND + (k - HID)] = (f16)v;
}

// ---------------------------------------------------------------------------
// gemm1 v3 (MFMA, single-pass over x): xw[m][n] = sum_k x[m][k]*WxT[n][k]+bsu
// Grid (2048,1): block = 64 m-rows x ALL 512 n. 256 threads (4 waves).
// Wave w: rows m0+16w+ (l&15); acc[32] f32x4 = 128 VGPR (full n range).
// WxT K-slice (512 rows x 32 k = 32 KB) staged in LDS, double-buffered;
// layout [kg][n] (f16x8 units) -> consumer quarter-wave reads 16B contiguous.
// x read ONCE from HBM (32 B/lane contiguous). Epilogue: LDS transpose ->
// coalesced f16x8 global stores.
// ---------------------------------------------------------------------------
__global__ __launch_bounds__(256, 2) void gemm1_kernel(const float* __restrict__ x,
                                                       const f16* __restrict__ WxT,
                                                       const float* __restrict__ bsu,
                                                       f16* __restrict__ xw) {
  __shared__ __align__(16) char smem[65536];
  f16x8* Bbuf0 = (f16x8*)smem;            // 2048 f16x8 = 32 KB
  f16x8* Bbuf1 = (f16x8*)(smem + 32768);

  const int m0 = blockIdx.x * 64;
  const int tid = threadIdx.x;
  const int w = tid >> 6, l = tid & 63;
  const int r16 = l & 15;   // A-row / B-col within 16-tile
  const int kg  = l >> 4;   // k-subgroup (8 wide)
  const int arow = m0 + w * 16 + r16;

  f32x4 acc[32];
#pragma unroll
  for (int nt = 0; nt < 32; ++nt) {
    float bv = bsu[nt * 16 + r16];
    acc[nt] = (f32x4){bv, bv, bv, bv};
  }

  // prologue stage kb=0 into Bbuf0
#pragma unroll
  for (int i = 0; i < 8; ++i) {
    int c = tid + 256 * i;  // 0..2047
    int n = c >> 2;
    int g = c & 3;
    Bbuf0[g * 512 + n] = *(const f16x8*)&WxT[(size_t)n * IND + 0 + g * 8];
  }
  __syncthreads();

#pragma unroll
  for (int kb = 0; kb < 8; ++kb) {
    f16x8* Bc = (kb & 1) ? Bbuf1 : Bbuf0;
    f16x8* Bn = (kb & 1) ? Bbuf0 : Bbuf1;
    if (kb + 1 < 8) {
      const int k0n = (kb + 1) * 32;
#pragma unroll
      for (int i = 0; i < 8; ++i) {
        int c = tid + 256 * i;
        int n = c >> 2;
        int g = c & 3;
        Bn[g * 512 + n] = *(const f16x8*)&WxT[(size_t)n * IND + k0n + g * 8];
      }
    }
    // A fragment: 8 consecutive f32 -> f16x8
    const float4* ap = (const float4*)&x[(size_t)arow * IND + kb * 32 + kg * 8];
    float4 a0 = ap[0], a1 = ap[1];
    f16x8 afrag = {(f16)a0.x, (f16)a0.y, (f16)a0.z, (f16)a0.w,
                   (f16)a1.x, (f16)a1.y, (f16)a1.z, (f16)a1.w};
#pragma unroll
    for (int nt = 0; nt < 32; ++nt) {
      f16x8 bfrag = Bc[kg * 512 + nt * 16 + r16];
      acc[nt] = __builtin_amdgcn_mfma_f32_16x16x32_f16(afrag, bfrag, acc[nt], 0, 0, 0);
    }
    __syncthreads();
  }

  // epilogue: acc -> LDS f16 tile [64][512] -> coalesced global stores
  f16* Ot = (f16*)smem;
#pragma unroll
  for (int nt = 0; nt < 32; ++nt) {
#pragma unroll
    for (int r = 0; r < 4; ++r) {
      int row = w * 16 + kg * 4 + r;   // C/D layout: row=(lane>>4)*4+reg
      Ot[row * 512 + nt * 16 + r16] = (f16)acc[nt][r];
    }
  }
  __syncthreads();
#pragma unroll
  for (int i = 0; i < 16; ++i) {
    int c = tid + 256 * i;            // 4096 chunks of 8 f16
    int row = c >> 6;
    int co = (c & 63) * 8;
    *(f16x8*)&xw[(size_t)(m0 + row) * HID + co] = *(const f16x8*)&Ot[row * 512 + co];
  }
}

// ---------------------------------------------------------------------------
// scan v5 (R9, proven 1410us): 128 blocks x 512 threads (8 waves, 2/SIMD).
// Lane map: w=tid>>6, l=tid&63; kc=l&7 (64-k chunk); hq=l>>3 (row octet);
// thread owns rows hbase=w*64+hq*8 .. +7, k in [kc*64, kc*64+64).
// Rows 0..5 register-resident (192 f16x2); rows 6,7 streamed from LDS
// wl6/wl7[s][tid] (conflict-free contiguous b128).
// z-reads: 8 swizzled broadcast b128. Cross-chunk reduce in-register:
// xor7 (dpp 0x141) -> xor1 (0xB1) -> xor2 (0x4E). ONE barrier per step.
// ---------------------------------------------------------------------------
__global__ __launch_bounds__(512, 2) void scan_kernel(
    const f16* __restrict__ WzT, const f16* __restrict__ xw,
    const float* __restrict__ carry, const float* __restrict__ Wout,
    const float* __restrict__ bout, float* __restrict__ outp) {
  __shared__ __align__(16) f16 zsh[2][512];        // 2 KB double-buffered z
  __shared__ __align__(16) f16x8 wl6[8][512];      // 64 KB row-6 weights
  __shared__ __align__(16) f16x8 wl7[8][512];      // 64 KB row-7 weights
  __shared__ float red[512];                       // 2 KB epilogue

  const int b_ = blockIdx.x;
  const int tid = threadIdx.x;
  const int w = tid >> 6, l = tid & 63;
  const int kc = l & 7;
  const int hq = l >> 3;
  const int hbase = w * 64 + hq * 8;

  // rows hbase..hbase+5 -> registers, slice-permuted by (s^kc)
  f16x2 wreg[6][32];
#pragma unroll
  for (int r = 0; r < 6; ++r) {
#pragma unroll
    for (int s = 0; s < 8; ++s) {
      v8u v;
      v.v = *(const f16x8*)&WzT[(hbase + r) * HID + kc * 64 + ((s ^ kc) & 7) * 8];
#pragma unroll
      for (int p = 0; p < 4; ++p) wreg[r][s * 4 + p] = v.h[p];
    }
  }
  // opacity pin: prevent remat/sinking
#pragma unroll
  for (int r = 0; r < 6; ++r) {
#pragma unroll
    for (int s = 0; s < 32; ++s) {
      unsigned u = __builtin_bit_cast(unsigned, wreg[r][s]);
      asm volatile("" : "+v"(u));
      wreg[r][s] = __builtin_bit_cast(f16x2, u);
    }
  }
  // rows hbase+6, hbase+7 -> LDS in consumption order
#pragma unroll
  for (int s = 0; s < 8; ++s) {
    wl6[s][tid] = *(const f16x8*)&WzT[(hbase + 6) * HID + kc * 64 + ((s ^ kc) & 7) * 8];
    wl7[s][tid] = *(const f16x8*)&WzT[(hbase + 7) * HID + kc * 64 + ((s ^ kc) & 7) * 8];
  }

  // z^0 from carry, plain layout
  zsh[0][tid] = (f16)carry[b_ * HID + tid];

  // output row after pack-reduce: hbase + 4*b2 + 2*b0 + b1
  const int b0 = l & 1, b1 = (l >> 1) & 1, b2 = (l >> 2) & 1;
  const int myh = hbase + (b2 << 2) + (b0 << 1) + b1;

  float xw_cur = (float)xw[(size_t)b_ * SEQ * HID + myh];

  __syncthreads();

  float zlast = 0.f;
  for (int t = 0; t < SEQ; ++t) {
    const int p = t & 1;
    int tn = (t + 1 < SEQ) ? t + 1 : t;
    float xw_nxt = (float)xw[((size_t)b_ * SEQ + tn) * HID + myh];

    const f16* zb = &zsh[p][kc * 64];
    float a0 = 0.f, a1 = 0.f, a2 = 0.f, a3 = 0.f;
    float a4 = 0.f, a5 = 0.f, a6 = 0.f, a7 = 0.f;
#pragma unroll
    for (int s = 0; s < 8; ++s) {
      v8u zc, w6, w7;
      zc.v = *(const f16x8*)&zb[((s ^ kc) & 7) * 8];  // broadcast, bank-spread
      w6.v = wl6[s][tid];
      w7.v = wl7[s][tid];
#pragma unroll
      for (int q4 = 0; q4 < 4; ++q4) {
        f16x2 zp = zc.h[q4];
        int pi = s * 4 + q4;
        a0 = fdot2(zp, wreg[0][pi], a0);
        a1 = fdot2(zp, wreg[1][pi], a1);
        a2 = fdot2(zp, wreg[2][pi], a2);
        a3 = fdot2(zp, wreg[3][pi], a3);
        a4 = fdot2(zp, wreg[4][pi], a4);
        a5 = fdot2(zp, wreg[5][pi], a5);
        a6 = fdot2(zp, w6.h[q4], a6);
        a7 = fdot2(zp, w7.h[q4], a7);
      }
    }

    // ---- in-register pack-reduce over kc (lane bits 0,1,2) ----
    float n0_ = b2 ? a4 : a0, s0_ = b2 ? a0 : a4;
    float n1_ = b2 ? a5 : a1, s1_ = b2 ? a1 : a5;
    float n2_ = b2 ? a6 : a2, s2_ = b2 ? a2 : a6;
    float n3_ = b2 ? a7 : a3, s3_ = b2 ? a3 : a7;
    n0_ += fdpp<0x141>(s0_);
    n1_ += fdpp<0x141>(s1_);
    n2_ += fdpp<0x141>(s2_);
    n3_ += fdpp<0x141>(s3_);
    float m0_ = b0 ? n2_ : n0_, t0_ = b0 ? n0_ : n2_;
    float m1_ = b0 ? n3_ : n1_, t1_ = b0 ? n1_ : n3_;
    m0_ += fdpp<0xB1>(t0_);
    m1_ += fdpp<0xB1>(t1_);
    float f0_ = b1 ? m1_ : m0_, g0_ = b1 ? m0_ : m1_;
    float tot = f0_ + fdpp<0x4E>(g0_);

    float z = tanh_fast(tot + xw_cur);
    zlast = z;
    zsh[p ^ 1][myh] = (f16)z;
    __syncthreads();
    xw_cur = xw_nxt;
  }

  // outputs: z_last (f32, exact from register) + out[b] GEMV
  outp[BATCH + (size_t)b_ * HID + myh] = zlast;
  red[myh] = zlast * Wout[myh];
  __syncthreads();
  if (tid < 64) {
    float s2 = 0.f;
#pragma unroll
    for (int i = 0; i < 8; ++i) s2 += red[tid + 64 * i];
    red[tid] = s2;
  }
  __syncthreads();
  if (tid == 0) {
    float s3 = 0.f;
    for (int i = 0; i < 64; ++i) s3 += red[i];
    outp[b_] = s3 + bout[0];
  }
}

// ---------------------------------------------------------------------------
extern "C" void kernel_launch(void* const* d_in, const int* in_sizes, int n_in,
                              void* d_out, int out_size, void* d_ws, size_t ws_size,
                              hipStream_t stream) {
  const float* x     = (const float*)d_in[0];
  const float* carry = (const float*)d_in[1];
  const float* Wsu   = (const float*)d_in[2];
  const float* bsu   = (const float*)d_in[3];
  const float* Wout  = (const float*)d_in[4];
  const float* bout  = (const float*)d_in[5];
  float* outp = (float*)d_out;

  char* ws = (char*)d_ws;
  f16* WzT = (f16*)(ws);                        // 512 KB
  f16* WxT = (f16*)(ws + 512 * 1024);           // 256 KB
  f16* xw  = (f16*)(ws + 768 * 1024);           // 128 MB (131072*512*2B)

  prep_kernel<<<dim3((768 * 512) / 256), 256, 0, stream>>>(Wsu, WzT, WxT);
  gemm1_kernel<<<dim3(BATCH * SEQ / 64), 256, 0, stream>>>(x, WxT, bsu, xw);
  scan_kernel<<<dim3(BATCH), 512, 0, stream>>>(WzT, xw, carry, Wout, bout, outp);
}